// Round 14
// baseline (590.903 us; speedup 1.0000x reference)
//
#include <hip/hip_runtime.h>
#include <math.h>

#define LVL 16
#define TBL (1u << 19)
#define PR1 2654435761u
#define PR2 805459861u
#define NDENSE 7
#define NHASH 9

typedef __attribute__((ext_vector_type(4))) float f4;
typedef __attribute__((ext_vector_type(4))) unsigned u4;
typedef __attribute__((ext_vector_type(8))) short bf16x8;
typedef __attribute__((ext_vector_type(4))) float f32x4;

union FragU { unsigned u[4]; bf16x8 v; };

// ---------------- params ----------------------------------------------------
struct EncParams {              // fallback (all 16 levels)
    float resf[LVL];
    float resm1[LVL];
    unsigned s1[LVL];
    unsigned s2[LVL];
    unsigned dense_mask;
};

struct FinalParams {            // fast path: all 7 dense levels via 32B cells
    float resf[NDENSE];
    float resm1[NDENSE];
    unsigned cellbase[NDENSE];  // byte offset of cell table
    unsigned cres[NDENSE];      // res   (cell stride y)
    unsigned cres2[NDENSE];     // res^2 (cell stride z)
};

struct CellBuild {
    unsigned nc[NDENSE];        // res^3
    unsigned res[NDENSE];
    unsigned s1[NDENSE], s2[NDENSE];
    unsigned dst_dw[NDENSE];
};

// bf16 round-to-nearest-even
static __device__ __forceinline__ unsigned f2bf(float f) {
    unsigned u = __float_as_uint(f);
    u += 0x7FFFu + ((u >> 16) & 1u);
    return u >> 16;
}
static __device__ __forceinline__ float bf_lo(unsigned p) { return __uint_as_float(p << 16); }
static __device__ __forceinline__ float bf_hi(unsigned p) { return __uint_as_float(p & 0xFFFF0000u); }

static __device__ __forceinline__ float fast_tanh(float v) {
    v = fminf(fmaxf(v, -10.f), 10.f);
    float e = __expf(2.0f * v);
    return __fdividef(e - 1.0f, e + 1.0f);
}

// static 2-bit select from u4 (3 cndmasks, no dynamic indexing)
static __device__ __forceinline__ unsigned sel4(u4 v, unsigned q) {
    unsigned t0 = (q & 1u) ? v[1] : v[0];
    unsigned t1 = (q & 1u) ? v[3] : v[2];
    return (q & 2u) ? t1 : t0;
}

// ---- proven-safe single-block gathers (issue + internal drain) -------------
static __device__ __forceinline__ void gather8_sc0(const unsigned* __restrict__ tb,
                                                   const unsigned* off, unsigned* val)
{
    asm volatile(
        "global_load_dword %0, %8, %16 sc0\n\t"
        "global_load_dword %1, %9, %16 sc0\n\t"
        "global_load_dword %2, %10, %16 sc0\n\t"
        "global_load_dword %3, %11, %16 sc0\n\t"
        "global_load_dword %4, %12, %16 sc0\n\t"
        "global_load_dword %5, %13, %16 sc0\n\t"
        "global_load_dword %6, %14, %16 sc0\n\t"
        "global_load_dword %7, %15, %16 sc0\n\t"
        "s_waitcnt vmcnt(0)"
        : "=&v"(val[0]), "=&v"(val[1]), "=&v"(val[2]), "=&v"(val[3]),
          "=&v"(val[4]), "=&v"(val[5]), "=&v"(val[6]), "=&v"(val[7])
        : "v"(off[0]), "v"(off[1]), "v"(off[2]), "v"(off[3]),
          "v"(off[4]), "v"(off[5]), "v"(off[6]), "v"(off[7]),
          "s"(tb)
        : "memory");
}

// 10 aligned 16B gathers (one internal drain) — cell levels 0..4
static __device__ __forceinline__ void gather10x4_sc0(const unsigned* __restrict__ tb,
                                                      const unsigned* off, u4* val)
{
    asm volatile(
        "global_load_dwordx4 %0, %10, %20 sc0\n\t"
        "global_load_dwordx4 %1, %11, %20 sc0\n\t"
        "global_load_dwordx4 %2, %12, %20 sc0\n\t"
        "global_load_dwordx4 %3, %13, %20 sc0\n\t"
        "global_load_dwordx4 %4, %14, %20 sc0\n\t"
        "global_load_dwordx4 %5, %15, %20 sc0\n\t"
        "global_load_dwordx4 %6, %16, %20 sc0\n\t"
        "global_load_dwordx4 %7, %17, %20 sc0\n\t"
        "global_load_dwordx4 %8, %18, %20 sc0\n\t"
        "global_load_dwordx4 %9, %19, %20 sc0\n\t"
        "s_waitcnt vmcnt(0)"
        : "=&v"(val[0]), "=&v"(val[1]), "=&v"(val[2]), "=&v"(val[3]), "=&v"(val[4]),
          "=&v"(val[5]), "=&v"(val[6]), "=&v"(val[7]), "=&v"(val[8]), "=&v"(val[9])
        : "v"(off[0]), "v"(off[1]), "v"(off[2]), "v"(off[3]), "v"(off[4]),
          "v"(off[5]), "v"(off[6]), "v"(off[7]), "v"(off[8]), "v"(off[9]),
          "s"(tb)
        : "memory");
}

// 4 aligned 16B gathers (one internal drain)
static __device__ __forceinline__ void gather4x4_sc0(const unsigned* __restrict__ tb,
                                                     const unsigned* off, u4* val)
{
    asm volatile(
        "global_load_dwordx4 %0, %4, %8 sc0\n\t"
        "global_load_dwordx4 %1, %5, %8 sc0\n\t"
        "global_load_dwordx4 %2, %6, %8 sc0\n\t"
        "global_load_dwordx4 %3, %7, %8 sc0\n\t"
        "s_waitcnt vmcnt(0)"
        : "=&v"(val[0]), "=&v"(val[1]), "=&v"(val[2]), "=&v"(val[3])
        : "v"(off[0]), "v"(off[1]), "v"(off[2]), "v"(off[3]),
          "s"(tb)
        : "memory");
}

// ---------------- prep: weight-norm + bf16-pack w1 --------------------------
// ws dword layout: [0,2048) w1 f32 | [2048,2240) w2 f32 | [2304,3328) w1 bf16x2
__global__ __launch_bounds__(256)
void prep_weights(const float* __restrict__ v1, const float* __restrict__ g1,
                  const float* __restrict__ v2, const float* __restrict__ g2,
                  float* __restrict__ ws)
{
    int t = threadIdx.x;
    if (t < 64) {
        float row[32];
        float s = 0.f;
        for (int i = 0; i < 32; ++i) { row[i] = v1[t * 32 + i]; s += row[i] * row[i]; }
        float sc = g1[t] / sqrtf(s);
        unsigned* wbf = (unsigned*)ws + 2304;
        for (int i = 0; i < 32; ++i) ws[t * 32 + i] = row[i] * sc;
        for (int w = 0; w < 16; ++w)
            wbf[t * 16 + w] = (f2bf(row[2 * w + 1] * sc) << 16) | f2bf(row[2 * w] * sc);
    } else if (t < 67) {
        int r = t - 64;
        float s = 0.f;
        for (int i = 0; i < 64; ++i) { float v = v2[r * 64 + i]; s += v * v; }
        float scale = g2[r] / sqrtf(s);
        for (int i = 0; i < 64; ++i) ws[2048 + r * 64 + i] = v2[r * 64 + i] * scale;
    }
}

// ---------------- convert tables fp32 -> packed bf16x2 (streaming) ----------
__global__ __launch_bounds__(256)
void convert_tables(const float* __restrict__ src, unsigned* __restrict__ dst, int npairs)
{
    int j = blockIdx.x * 256 + threadIdx.x;
    if (j >= npairs) return;
    f4 v = __builtin_nontemporal_load((const f4*)src + j);
    unsigned lo = (f2bf(v.y) << 16) | f2bf(v.x);
    unsigned hi = (f2bf(v.w) << 16) | f2bf(v.z);
    unsigned long long o = ((unsigned long long)hi << 32) | lo;
    __builtin_nontemporal_store(o, (unsigned long long*)dst + j);
}

// ---------------- build 32B cell tables (levels 0..6) -----------------------
// cell c=(cx,cy,cz), word k = corner (xb=k&1, yb=(k>>1)&1, zb=k>>2)
__global__ __launch_bounds__(256)
void build_cell(const float* __restrict__ tables, unsigned* __restrict__ region, CellBuild cb)
{
    int l = blockIdx.y;
    unsigned c = blockIdx.x * 256 + threadIdx.x;
    if (c >= cb.nc[l]) return;
    unsigned res = cb.res[l];
    unsigned cx = c % res, t = c / res;
    unsigned cy = t % res, cz = t / res;
    unsigned s1 = cb.s1[l], s2 = cb.s2[l];
    unsigned base = cx + cy * s1 + cz * s2;
    const float* src = tables + (size_t)l * TBL * 2;
    unsigned o[8];
#pragma unroll
    for (int k = 0; k < 8; ++k) {
        unsigned e = base + (k & 1u) + ((k >> 1) & 1u) * s1 + (k >> 2) * s2;
        o[k] = (f2bf(src[2 * e + 1]) << 16) | f2bf(src[2 * e]);
    }
    u4* dst = (u4*)(region + cb.dst_dw[l] + 8u * c);
    u4 o0 = {o[0], o[1], o[2], o[3]};
    u4 o1 = {o[4], o[5], o[6], o[7]};
    dst[0] = o0; dst[1] = o1;
}

// ---------------- per-hash-level encode: 4 pts/thread -----------------------
// x-corner pair {c0^R, (c0+1)^R}: for c0 % 4 != 3, d = c0^(c0+1) is 1 or 3 and
// both corners lie in the same aligned 4-entry (16B) block -> ONE dwordx4 per
// (y,z)-combo = 4 requests/pt (75% of points). c0 % 4 == 3: 8-dword path.
__global__ __launch_bounds__(256, 4)
void encode_hash4(const float* __restrict__ x, const unsigned* __restrict__ tb,
                  unsigned* __restrict__ hout, int N, float rf, float rm1)
{
    int j = blockIdx.x * 256 + threadIdx.x;
    int i0 = 4 * j;
    if (i0 >= N) return;

    if (i0 + 4 <= N) {
        const f4* xp = (const f4*)(x + (size_t)3 * i0);
        f4 q0 = __builtin_nontemporal_load(xp);
        f4 q1 = __builtin_nontemporal_load(xp + 1);
        f4 q2 = __builtin_nontemporal_load(xp + 2);
        float n0[4], n1[4], n2[4];
        n0[0] = (q0.x + 1.f) * 0.5f; n1[0] = (q0.y + 1.f) * 0.5f; n2[0] = (q0.z + 1.f) * 0.5f;
        n0[1] = (q0.w + 1.f) * 0.5f; n1[1] = (q1.x + 1.f) * 0.5f; n2[1] = (q1.y + 1.f) * 0.5f;
        n0[2] = (q1.z + 1.f) * 0.5f; n1[2] = (q1.w + 1.f) * 0.5f; n2[2] = (q2.x + 1.f) * 0.5f;
        n0[3] = (q2.y + 1.f) * 0.5f; n1[3] = (q2.z + 1.f) * 0.5f; n2[3] = (q2.w + 1.f) * 0.5f;

        unsigned o[4];
#pragma unroll
        for (int p = 0; p < 4; ++p) {
            float a0 = n0[p] * rf, a1 = n1[p] * rf, a2 = n2[p] * rf;
            float w0 = fminf(floorf(a0), rm1);
            float w1 = fminf(floorf(a1), rm1);
            float w2 = fminf(floorf(a2), rm1);
            float f0 = a0 - w0, f1 = a1 - w1, f2 = a2 - w2;
            unsigned c0 = (unsigned)w0;
            unsigned hx0 = c0;
            unsigned hy0 = (unsigned)w1 * PR1, hy1 = hy0 + PR1;
            unsigned hz0 = (unsigned)w2 * PR2, hz1 = hz0 + PR2;
            float wx1 = f0, wx0 = 1.f - f0;

            float acc0, acc1;
            if ((c0 & 3u) != 3u) {
                // d = 1 (even) or 3 (c0 % 4 == 1): pair within aligned-4 block
                unsigned d = (c0 & 1u) ? 3u : 1u;
                unsigned offb[4], qs[4];
#pragma unroll
                for (int jj = 0; jj < 4; ++jj) {
                    unsigned hyv = (jj & 2) ? hy1 : hy0;
                    unsigned hzv = (jj & 1) ? hz1 : hz0;
                    unsigned idx0 = (hx0 ^ hyv ^ hzv) & (TBL - 1u);
                    qs[jj] = idx0 & 3u;
                    offb[jj] = (idx0 & ~3u) << 2;
                }
                u4 bv[4];
                gather4x4_sc0(tb, offb, bv);
                acc0 = 0.f; acc1 = 0.f;
#pragma unroll
                for (int jj = 0; jj < 4; ++jj) {
                    unsigned q = qs[jj];
                    unsigned x0v = sel4(bv[jj], q);        // corner x = c0
                    unsigned x1v = sel4(bv[jj], q ^ d);    // corner x = c0+1
                    float wyz = ((jj & 2) ? f1 : 1.f - f1) * ((jj & 1) ? f2 : 1.f - f2);
                    acc0 = fmaf(wyz, fmaf(wx0, bf_lo(x0v), wx1 * bf_lo(x1v)), acc0);
                    acc1 = fmaf(wyz, fmaf(wx0, bf_hi(x0v), wx1 * bf_hi(x1v)), acc1);
                }
            } else {
                unsigned hx1 = c0 + 1u;
                unsigned off[8];
#pragma unroll
                for (int c = 0; c < 8; ++c) {
                    unsigned hx = (c & 4) ? hx1 : hx0;
                    unsigned hy = (c & 2) ? hy1 : hy0;
                    unsigned hz = (c & 1) ? hz1 : hz0;
                    off[c] = ((hx ^ hy ^ hz) & (TBL - 1u)) << 2;
                }
                unsigned v[8];
                gather8_sc0(tb, off, v);
                acc0 = 0.f; acc1 = 0.f;
#pragma unroll
                for (int c = 0; c < 8; ++c) {
                    float w = ((c & 4) ? f0 : 1.f - f0) *
                              ((c & 2) ? f1 : 1.f - f1) *
                              ((c & 1) ? f2 : 1.f - f2);
                    acc0 = fmaf(w, bf_lo(v[c]), acc0);
                    acc1 = fmaf(w, bf_hi(v[c]), acc1);
                }
            }
            o[p] = (f2bf(acc1) << 16) | f2bf(acc0);
        }
        u4 ov = {o[0], o[1], o[2], o[3]};
        __builtin_nontemporal_store(ov, (u4*)(hout + i0));
    } else {
        for (int i = i0; i < N; ++i) {
            float xn0 = (x[3 * i + 0] + 1.0f) * 0.5f;
            float xn1 = (x[3 * i + 1] + 1.0f) * 0.5f;
            float xn2 = (x[3 * i + 2] + 1.0f) * 0.5f;
            float p0 = xn0 * rf, p1 = xn1 * rf, p2 = xn2 * rf;
            float pf0 = fminf(floorf(p0), rm1), pf1 = fminf(floorf(p1), rm1), pf2 = fminf(floorf(p2), rm1);
            float fg0 = p0 - pf0, fg1 = p1 - pf1, fg2 = p2 - pf2;
            unsigned hx0 = (unsigned)pf0, hx1 = hx0 + 1u;
            unsigned hy0 = (unsigned)pf1 * PR1, hy1 = hy0 + PR1;
            unsigned hz0 = (unsigned)pf2 * PR2, hz1 = hz0 + PR2;
            float a0 = 0.f, a1 = 0.f;
#pragma unroll
            for (int c = 0; c < 8; ++c) {
                unsigned hxv = (c & 4) ? hx1 : hx0;
                unsigned hyv = (c & 2) ? hy1 : hy0;
                unsigned hzv = (c & 1) ? hz1 : hz0;
                unsigned vv = tb[(hxv ^ hyv ^ hzv) & (TBL - 1u)];
                float w = ((c & 4) ? fg0 : 1.f - fg0) * ((c & 2) ? fg1 : 1.f - fg1) * ((c & 1) ? fg2 : 1.f - fg2);
                a0 = fmaf(w, bf_lo(vv), a0);
                a1 = fmaf(w, bf_hi(vv), a1);
            }
            hout[i] = (f2bf(a1) << 16) | f2bf(a0);
        }
    }
}

// trilinear blend of one 32B cell (two 16B halves, z=0/1)
static __device__ __forceinline__ unsigned blend_cell(u4 e0, u4 e1,
                                                      float fx, float fy, float fz)
{
    float wx1 = fx, wx0 = 1.f - fx;
    float wy1 = fy, wy0 = 1.f - fy;
    float lo0 = wy0 * fmaf(wx0, bf_lo(e0[0]), wx1 * bf_lo(e0[1]))
              + wy1 * fmaf(wx0, bf_lo(e0[2]), wx1 * bf_lo(e0[3]));
    float hi0 = wy0 * fmaf(wx0, bf_hi(e0[0]), wx1 * bf_hi(e0[1]))
              + wy1 * fmaf(wx0, bf_hi(e0[2]), wx1 * bf_hi(e0[3]));
    float lo1 = wy0 * fmaf(wx0, bf_lo(e1[0]), wx1 * bf_lo(e1[1]))
              + wy1 * fmaf(wx0, bf_lo(e1[2]), wx1 * bf_lo(e1[3]));
    float hi1 = wy0 * fmaf(wx0, bf_hi(e1[0]), wx1 * bf_hi(e1[1]))
              + wy1 * fmaf(wx0, bf_hi(e1[2]), wx1 * bf_hi(e1[3]));
    float acc0 = (1.f - fz) * lo0 + fz * lo1;
    float acc1 = (1.f - fz) * hi0 + fz * hi1;
    return (f2bf(acc1) << 16) | f2bf(acc0);
}

// ---------------- final: 7 cell levels + hbuf + MFMA MLP --------------------
// Requires N % 256 == 0 (guaranteed by fast-path guard).
__global__ __launch_bounds__(256, 6)
void final_mfma(const float* __restrict__ x, const unsigned* __restrict__ tb,
                const unsigned* __restrict__ hbuf, const unsigned* __restrict__ w1bf,
                const float* __restrict__ b1, const float* __restrict__ w2,
                const float* __restrict__ b2, float* __restrict__ out,
                int N, FinalParams dp)
{
    __shared__ unsigned lds[256 * 20];   // 80B-stride rows, 16B-aligned chunks
    int tid = threadIdx.x;
    int i = blockIdx.x * 256 + tid;

    unsigned hp[NHASH];
#pragma unroll
    for (int l = 0; l < NHASH; ++l)
        hp[l] = __builtin_nontemporal_load(hbuf + (size_t)l * N + i);

    float xn0 = (__builtin_nontemporal_load(x + 3 * i + 0) + 1.0f) * 0.5f;
    float xn1 = (__builtin_nontemporal_load(x + 3 * i + 1) + 1.0f) * 0.5f;
    float xn2 = (__builtin_nontemporal_load(x + 3 * i + 2) + 1.0f) * 0.5f;

    float fr[NDENSE][3];
    unsigned offs[2 * NDENSE];
#pragma unroll
    for (int l = 0; l < NDENSE; ++l) {
        float rf = dp.resf[l];
        float p0 = xn0 * rf, p1 = xn1 * rf, p2 = xn2 * rf;
        float pf0 = fminf(floorf(p0), dp.resm1[l]);
        float pf1 = fminf(floorf(p1), dp.resm1[l]);
        float pf2 = fminf(floorf(p2), dp.resm1[l]);
        fr[l][0] = p0 - pf0; fr[l][1] = p1 - pf1; fr[l][2] = p2 - pf2;
        unsigned c = (unsigned)pf0 + (unsigned)pf1 * dp.cres[l] + (unsigned)pf2 * dp.cres2[l];
        unsigned base = dp.cellbase[l] + c * 32u;
        offs[2 * l + 0] = base;
        offs[2 * l + 1] = base + 16u;
    }

    unsigned hw[16];
    {
        u4 xv[10];
        gather10x4_sc0(tb, offs, xv);
#pragma unroll
        for (int l = 0; l < 5; ++l)
            hw[l] = blend_cell(xv[2 * l], xv[2 * l + 1], fr[l][0], fr[l][1], fr[l][2]);
    }
    {
        u4 yv[4];
        gather4x4_sc0(tb, offs + 10, yv);
        hw[5] = blend_cell(yv[0], yv[1], fr[5][0], fr[5][1], fr[5][2]);
        hw[6] = blend_cell(yv[2], yv[3], fr[6][0], fr[6][1], fr[6][2]);
    }
#pragma unroll
    for (int l = 0; l < NHASH; ++l) hw[NDENSE + l] = hp[l];

    unsigned* row = &lds[tid * 20];
#pragma unroll
    for (int c = 0; c < 4; ++c)
        *(uint4*)(row + 4 * c) = make_uint4(hw[4 * c], hw[4 * c + 1], hw[4 * c + 2], hw[4 * c + 3]);

    __syncthreads();

    // ---- phase B: MFMA MLP, 16 points per group, 4 groups per wave ----
    int lane = tid & 63;
    int wv   = tid >> 6;
    int l16  = lane & 15;
    int lhi  = lane >> 4;

    bf16x8 bfr[4];
#pragma unroll
    for (int t = 0; t < 4; ++t) {
        const unsigned* p = w1bf + (t * 16 + l16) * 16 + lhi * 4;
        FragU u;
        u.u[0] = p[0]; u.u[1] = p[1]; u.u[2] = p[2]; u.u[3] = p[3];
        bfr[t] = u.v;
    }
    float b1v[4];
#pragma unroll
    for (int t = 0; t < 4; ++t) b1v[t] = b1[t * 16 + l16];
    float w2v[3][4];
#pragma unroll
    for (int jj = 0; jj < 3; ++jj)
#pragma unroll
        for (int t = 0; t < 4; ++t) w2v[jj][t] = w2[jj * 64 + t * 16 + l16];
    float bias2 = (l16 < 3) ? b2[l16] : 0.f;

#pragma unroll
    for (int g = 0; g < 4; ++g) {
        const unsigned* rp = &lds[(wv * 64 + g * 16 + l16) * 20 + lhi * 4];
        FragU u;
        u.u[0] = rp[0]; u.u[1] = rp[1]; u.u[2] = rp[2]; u.u[3] = rp[3];
        bf16x8 af = u.v;

        f32x4 acc[4];
#pragma unroll
        for (int t = 0; t < 4; ++t) {
            f32x4 z = {0.f, 0.f, 0.f, 0.f};
            acc[t] = __builtin_amdgcn_mfma_f32_16x16x32_bf16(af, bfr[t], z, 0, 0, 0);
        }

#pragma unroll
        for (int r = 0; r < 4; ++r) {
            float p0 = 0.f, p1 = 0.f, p2 = 0.f;
#pragma unroll
            for (int t = 0; t < 4; ++t) {
                float a = fmaxf(acc[t][r] + b1v[t], 0.f);
                p0 = fmaf(a, w2v[0][t], p0);
                p1 = fmaf(a, w2v[1][t], p1);
                p2 = fmaf(a, w2v[2][t], p2);
            }
#pragma unroll
            for (int m = 1; m < 16; m <<= 1) {
                p0 += __shfl_xor(p0, m);
                p1 += __shfl_xor(p1, m);
                p2 += __shfl_xor(p2, m);
            }
            if (l16 < 3) {
                int point = blockIdx.x * 256 + wv * 64 + g * 16 + lhi * 4 + r;
                float v = (l16 == 0) ? p0 : ((l16 == 1) ? p1 : p2);
                out[(size_t)point * 3 + l16] = fast_tanh(v + bias2);
            }
        }
    }
}

// ---------------- fallback: round-1 fused kernel (proven correct) -----------
__global__ __launch_bounds__(256)
void fused_ngp(const float* __restrict__ x, const float* __restrict__ tables,
               const float* __restrict__ w1, const float* __restrict__ b1,
               const float* __restrict__ w2, const float* __restrict__ b2,
               float* __restrict__ out, int N, EncParams ep)
{
    int i = blockIdx.x * 256 + threadIdx.x;
    if (i >= N) return;

    float xn0 = (x[3 * i + 0] + 1.0f) * 0.5f;
    float xn1 = (x[3 * i + 1] + 1.0f) * 0.5f;
    float xn2 = (x[3 * i + 2] + 1.0f) * 0.5f;

    float h[2 * LVL];

#pragma unroll
    for (int l = 0; l < LVL; ++l) {
        float rf = ep.resf[l];
        float p0 = xn0 * rf, p1 = xn1 * rf, p2 = xn2 * rf;
        float pf0 = fminf(floorf(p0), ep.resm1[l]);
        float pf1 = fminf(floorf(p1), ep.resm1[l]);
        float pf2 = fminf(floorf(p2), ep.resm1[l]);
        float fr0 = p0 - pf0, fr1 = p1 - pf1, fr2 = p2 - pf2;
        unsigned c0 = (unsigned)pf0, c1 = (unsigned)pf1, c2 = (unsigned)pf2;
        const float2* tb = (const float2*)tables + (size_t)l * TBL;

        float acc0 = 0.f, acc1 = 0.f;
        if ((ep.dense_mask >> l) & 1u) {
            unsigned s1 = ep.s1[l], s2 = ep.s2[l];
            unsigned b = c0 + c1 * s1 + c2 * s2;
#pragma unroll
            for (int c = 0; c < 8; ++c) {
                unsigned id = b + ((c & 4) ? 1u : 0u) + ((c & 2) ? s1 : 0u) + ((c & 1) ? s2 : 0u);
                float2 v = tb[id];
                float w = ((c & 4) ? fr0 : 1.f - fr0) * ((c & 2) ? fr1 : 1.f - fr1) * ((c & 1) ? fr2 : 1.f - fr2);
                acc0 = fmaf(w, v.x, acc0);
                acc1 = fmaf(w, v.y, acc1);
            }
        } else {
            unsigned hx0 = c0, hx1 = c0 + 1u;
            unsigned hy0 = c1 * PR1, hy1 = hy0 + PR1;
            unsigned hz0 = c2 * PR2, hz1 = hz0 + PR2;
#pragma unroll
            for (int c = 0; c < 8; ++c) {
                unsigned hx = (c & 4) ? hx1 : hx0;
                unsigned hy = (c & 2) ? hy1 : hy0;
                unsigned hz = (c & 1) ? hz1 : hz0;
                float2 v = tb[(hx ^ hy ^ hz) & (TBL - 1u)];
                float w = ((c & 4) ? fr0 : 1.f - fr0) * ((c & 2) ? fr1 : 1.f - fr1) * ((c & 1) ? fr2 : 1.f - fr2);
                acc0 = fmaf(w, v.x, acc0);
                acc1 = fmaf(w, v.y, acc1);
            }
        }
        h[2 * l + 0] = acc0;
        h[2 * l + 1] = acc1;
    }

    float r0 = b2[0], r1 = b2[1], r2 = b2[2];
    for (int o = 0; o < 64; ++o) {
        float a = b1[o];
#pragma unroll
        for (int k = 0; k < 32; ++k) a = fmaf(h[k], w1[o * 32 + k], a);
        a = fmaxf(a, 0.f);
        r0 = fmaf(a, w2[0 * 64 + o], r0);
        r1 = fmaf(a, w2[1 * 64 + o], r1);
        r2 = fmaf(a, w2[2 * 64 + o], r2);
    }
    out[3 * i + 0] = tanhf(r0);
    out[3 * i + 1] = tanhf(r1);
    out[3 * i + 2] = tanhf(r2);
}

// ---------------------------------------------------------------------------
extern "C" void kernel_launch(void* const* d_in, const int* in_sizes, int n_in,
                              void* d_out, int out_size, void* d_ws, size_t ws_size,
                              hipStream_t stream)
{
    const float* x      = (const float*)d_in[0];
    const float* tables = (const float*)d_in[1];
    const float* v1     = (const float*)d_in[2];
    const float* g1     = (const float*)d_in[3];
    const float* b1     = (const float*)d_in[4];
    const float* v2     = (const float*)d_in[5];
    const float* g2     = (const float*)d_in[6];
    const float* b2     = (const float*)d_in[7];
    float* out = (float*)d_out;
    float* ws  = (float*)d_ws;
    int N = in_sizes[0] / 3;

    // Replicate reference's double-precision level math exactly.
    EncParams ep;
    double Bd = exp(log(512.0 / 16.0) / (double)(LVL - 1));
    unsigned dm = 0;
    int resv[LVL];
    for (int l = 0; l < LVL; ++l) {
        int res = (int)floor(16.0 * pow(Bd, (double)l));
        resv[l] = res;
        ep.resf[l]  = (float)res;
        ep.resm1[l] = (float)(res - 1);
        long long rp1 = (long long)res + 1;
        if (rp1 * rp1 * rp1 <= (long long)TBL) dm |= (1u << l);
        ep.s1[l] = (unsigned)(res + 1);
        ep.s2[l] = (unsigned)((res + 1) * (res + 1));
    }
    ep.dense_mask = dm;

    prep_weights<<<1, 256, 0, stream>>>(v1, g1, v2, g2, ws);

    // workspace layout (bytes):
    //   [0, 16K)              weights
    //   [16K, 16K+32M)        16 level slots (2MB each):
    //                           slots 0-4: cell tables (built from fp32 src)
    //                           slots 7-15: bf16 tables (encode)
    //                           slots 5,6: unused
    //   [+..]                 cell tables for levels 5, 6 (32B/cell)
    //   [+..]                 hbuf
    size_t tb_off_bytes = 16384;
    unsigned NC[NDENSE];
    for (int l = 0; l < NDENSE; ++l) {
        unsigned r = (unsigned)resv[l];
        NC[l] = r * r * r;
    }
    bool cell_ok = true;
    for (int l = 0; l < 5; ++l) if (8ull * NC[l] > TBL) cell_ok = false;

    unsigned cum_dw = LVL * TBL;
    cum_dw = (cum_dw + 15u) & ~15u;
    unsigned cell5_dw = cum_dw; cum_dw += (8u * NC[5] + 15u) & ~15u;
    unsigned cell6_dw = cum_dw; cum_dw += (8u * NC[6] + 15u) & ~15u;
    size_t h_off_bytes = tb_off_bytes + (size_t)cum_dw * 4;
    size_t need = h_off_bytes + (size_t)NHASH * (size_t)N * 4;

    bool fast = (ws_size >= need) && (dm == 0x7Fu) && (N % 1024 == 0) && cell_ok;
    if (fast) {
        unsigned* tb   = (unsigned*)((char*)d_ws + tb_off_bytes);
        unsigned* hbuf = (unsigned*)((char*)d_ws + h_off_bytes);
        unsigned* w1bf = (unsigned*)ws + 2304;

        // convert only hash levels 7..15 (dense slots unused in fast path)
        int npairs = (int)((size_t)(LVL - NDENSE) * TBL / 2);
        convert_tables<<<(npairs + 255) / 256, 256, 0, stream>>>(
            tables + (size_t)NDENSE * TBL * 2, tb + (size_t)NDENSE * TBL, npairs);

        // 32B cell tables: levels 0-4 in-slot, 5-6 in extra region (fp32 source)
        CellBuild cb;
        unsigned maxNC = 0;
        for (int l = 0; l < NDENSE; ++l) {
            cb.nc[l] = NC[l]; cb.res[l] = (unsigned)resv[l];
            cb.s1[l] = ep.s1[l]; cb.s2[l] = ep.s2[l];
            cb.dst_dw[l] = (l < 5) ? (unsigned)l * TBL
                                   : ((l == 5) ? cell5_dw : cell6_dw);
            if (NC[l] > maxNC) maxNC = NC[l];
        }
        dim3 cgrid((maxNC + 255) / 256, NDENSE);
        build_cell<<<cgrid, 256, 0, stream>>>(tables, tb, cb);

        int grid4 = N / 1024;
        for (int l = 0; l < NHASH; ++l) {
            int gl = NDENSE + l;
            encode_hash4<<<grid4, 256, 0, stream>>>(
                x, tb + (size_t)gl * TBL, hbuf + (size_t)l * N, N,
                ep.resf[gl], ep.resm1[gl]);
        }

        FinalParams dp;
        for (int l = 0; l < NDENSE; ++l) {
            dp.resf[l] = ep.resf[l]; dp.resm1[l] = ep.resm1[l];
            dp.cellbase[l] = ((l < 5) ? (unsigned)l * TBL
                                      : ((l == 5) ? cell5_dw : cell6_dw)) * 4u;
            dp.cres[l] = (unsigned)resv[l];
            dp.cres2[l] = (unsigned)(resv[l] * resv[l]);
        }
        final_mfma<<<N / 256, 256, 0, stream>>>(x, tb, hbuf, w1bf, b1,
                                                ws + 2048, b2, out, N, dp);
    } else {
        fused_ngp<<<(N + 255) / 256, 256, 0, stream>>>(x, tables, ws, b1, ws + 2048, b2, out, N, ep);
    }
}

// Round 15
// 537.926 us; speedup vs baseline: 1.0985x; 1.0985x over previous
//
#include <hip/hip_runtime.h>
#include <math.h>

#define LVL 16
#define TBL (1u << 19)
#define PR1 2654435761u
#define PR2 805459861u
#define NDENSE 7
#define NHASH 9

typedef __attribute__((ext_vector_type(4))) float f4;
typedef __attribute__((ext_vector_type(4))) unsigned u4;
typedef __attribute__((ext_vector_type(8))) short bf16x8;
typedef __attribute__((ext_vector_type(4))) float f32x4;

union FragU { unsigned u[4]; bf16x8 v; };

// ---------------- params ----------------------------------------------------
struct EncParams {              // fallback (all 16 levels)
    float resf[LVL];
    float resm1[LVL];
    unsigned s1[LVL];
    unsigned s2[LVL];
    unsigned dense_mask;
};

struct FinalParams {            // fast path: all 7 dense levels via 32B cells
    float resf[NDENSE];
    float resm1[NDENSE];
    unsigned cellbase[NDENSE];  // byte offset of cell table
    unsigned cres[NDENSE];      // res   (cell stride y)
    unsigned cres2[NDENSE];     // res^2 (cell stride z)
};

struct CellBuild {
    unsigned nc[NDENSE];        // res^3
    unsigned res[NDENSE];
    unsigned s1[NDENSE], s2[NDENSE];
    unsigned dst_dw[NDENSE];
};

// bf16 round-to-nearest-even
static __device__ __forceinline__ unsigned f2bf(float f) {
    unsigned u = __float_as_uint(f);
    u += 0x7FFFu + ((u >> 16) & 1u);
    return u >> 16;
}
static __device__ __forceinline__ float bf_lo(unsigned p) { return __uint_as_float(p << 16); }
static __device__ __forceinline__ float bf_hi(unsigned p) { return __uint_as_float(p & 0xFFFF0000u); }

static __device__ __forceinline__ float fast_tanh(float v) {
    v = fminf(fmaxf(v, -10.f), 10.f);
    float e = __expf(2.0f * v);
    return __fdividef(e - 1.0f, e + 1.0f);
}

// static 2-bit select from u4 (3 cndmasks, no dynamic indexing)
static __device__ __forceinline__ unsigned sel4(u4 v, unsigned q) {
    unsigned t0 = (q & 1u) ? v[1] : v[0];
    unsigned t1 = (q & 1u) ? v[3] : v[2];
    return (q & 2u) ? t1 : t0;
}

// ---- proven-safe single-block gathers (issue + internal drain) -------------
static __device__ __forceinline__ void gather8_sc0(const unsigned* __restrict__ tb,
                                                   const unsigned* off, unsigned* val)
{
    asm volatile(
        "global_load_dword %0, %8, %16 sc0\n\t"
        "global_load_dword %1, %9, %16 sc0\n\t"
        "global_load_dword %2, %10, %16 sc0\n\t"
        "global_load_dword %3, %11, %16 sc0\n\t"
        "global_load_dword %4, %12, %16 sc0\n\t"
        "global_load_dword %5, %13, %16 sc0\n\t"
        "global_load_dword %6, %14, %16 sc0\n\t"
        "global_load_dword %7, %15, %16 sc0\n\t"
        "s_waitcnt vmcnt(0)"
        : "=&v"(val[0]), "=&v"(val[1]), "=&v"(val[2]), "=&v"(val[3]),
          "=&v"(val[4]), "=&v"(val[5]), "=&v"(val[6]), "=&v"(val[7])
        : "v"(off[0]), "v"(off[1]), "v"(off[2]), "v"(off[3]),
          "v"(off[4]), "v"(off[5]), "v"(off[6]), "v"(off[7]),
          "s"(tb)
        : "memory");
}

// 10 aligned 16B gathers (one internal drain) — cell levels 0..4
static __device__ __forceinline__ void gather10x4_sc0(const unsigned* __restrict__ tb,
                                                      const unsigned* off, u4* val)
{
    asm volatile(
        "global_load_dwordx4 %0, %10, %20 sc0\n\t"
        "global_load_dwordx4 %1, %11, %20 sc0\n\t"
        "global_load_dwordx4 %2, %12, %20 sc0\n\t"
        "global_load_dwordx4 %3, %13, %20 sc0\n\t"
        "global_load_dwordx4 %4, %14, %20 sc0\n\t"
        "global_load_dwordx4 %5, %15, %20 sc0\n\t"
        "global_load_dwordx4 %6, %16, %20 sc0\n\t"
        "global_load_dwordx4 %7, %17, %20 sc0\n\t"
        "global_load_dwordx4 %8, %18, %20 sc0\n\t"
        "global_load_dwordx4 %9, %19, %20 sc0\n\t"
        "s_waitcnt vmcnt(0)"
        : "=&v"(val[0]), "=&v"(val[1]), "=&v"(val[2]), "=&v"(val[3]), "=&v"(val[4]),
          "=&v"(val[5]), "=&v"(val[6]), "=&v"(val[7]), "=&v"(val[8]), "=&v"(val[9])
        : "v"(off[0]), "v"(off[1]), "v"(off[2]), "v"(off[3]), "v"(off[4]),
          "v"(off[5]), "v"(off[6]), "v"(off[7]), "v"(off[8]), "v"(off[9]),
          "s"(tb)
        : "memory");
}

// 4 aligned 16B gathers (one internal drain)
static __device__ __forceinline__ void gather4x4_sc0(const unsigned* __restrict__ tb,
                                                     const unsigned* off, u4* val)
{
    asm volatile(
        "global_load_dwordx4 %0, %4, %8 sc0\n\t"
        "global_load_dwordx4 %1, %5, %8 sc0\n\t"
        "global_load_dwordx4 %2, %6, %8 sc0\n\t"
        "global_load_dwordx4 %3, %7, %8 sc0\n\t"
        "s_waitcnt vmcnt(0)"
        : "=&v"(val[0]), "=&v"(val[1]), "=&v"(val[2]), "=&v"(val[3])
        : "v"(off[0]), "v"(off[1]), "v"(off[2]), "v"(off[3]),
          "s"(tb)
        : "memory");
}

// ---------------- prep: weight-norm + bf16-pack w1 --------------------------
// ws dword layout: [0,2048) w1 f32 | [2048,2240) w2 f32 | [2304,3328) w1 bf16x2
__global__ __launch_bounds__(256)
void prep_weights(const float* __restrict__ v1, const float* __restrict__ g1,
                  const float* __restrict__ v2, const float* __restrict__ g2,
                  float* __restrict__ ws)
{
    int t = threadIdx.x;
    if (t < 64) {
        float row[32];
        float s = 0.f;
        for (int i = 0; i < 32; ++i) { row[i] = v1[t * 32 + i]; s += row[i] * row[i]; }
        float sc = g1[t] / sqrtf(s);
        unsigned* wbf = (unsigned*)ws + 2304;
        for (int i = 0; i < 32; ++i) ws[t * 32 + i] = row[i] * sc;
        for (int w = 0; w < 16; ++w)
            wbf[t * 16 + w] = (f2bf(row[2 * w + 1] * sc) << 16) | f2bf(row[2 * w] * sc);
    } else if (t < 67) {
        int r = t - 64;
        float s = 0.f;
        for (int i = 0; i < 64; ++i) { float v = v2[r * 64 + i]; s += v * v; }
        float scale = g2[r] / sqrtf(s);
        for (int i = 0; i < 64; ++i) ws[2048 + r * 64 + i] = v2[r * 64 + i] * scale;
    }
}

// ---------------- convert tables fp32 -> packed bf16x2 (streaming) ----------
__global__ __launch_bounds__(256)
void convert_tables(const float* __restrict__ src, unsigned* __restrict__ dst, int npairs)
{
    int j = blockIdx.x * 256 + threadIdx.x;
    if (j >= npairs) return;
    f4 v = __builtin_nontemporal_load((const f4*)src + j);
    unsigned lo = (f2bf(v.y) << 16) | f2bf(v.x);
    unsigned hi = (f2bf(v.w) << 16) | f2bf(v.z);
    unsigned long long o = ((unsigned long long)hi << 32) | lo;
    __builtin_nontemporal_store(o, (unsigned long long*)dst + j);
}

// ---------------- build 32B cell tables (levels 0..6) -----------------------
// cell c=(cx,cy,cz), word k = corner (xb=k&1, yb=(k>>1)&1, zb=k>>2)
__global__ __launch_bounds__(256)
void build_cell(const float* __restrict__ tables, unsigned* __restrict__ region, CellBuild cb)
{
    int l = blockIdx.y;
    unsigned c = blockIdx.x * 256 + threadIdx.x;
    if (c >= cb.nc[l]) return;
    unsigned res = cb.res[l];
    unsigned cx = c % res, t = c / res;
    unsigned cy = t % res, cz = t / res;
    unsigned s1 = cb.s1[l], s2 = cb.s2[l];
    unsigned base = cx + cy * s1 + cz * s2;
    const float* src = tables + (size_t)l * TBL * 2;
    unsigned o[8];
#pragma unroll
    for (int k = 0; k < 8; ++k) {
        unsigned e = base + (k & 1u) + ((k >> 1) & 1u) * s1 + (k >> 2) * s2;
        o[k] = (f2bf(src[2 * e + 1]) << 16) | f2bf(src[2 * e]);
    }
    u4* dst = (u4*)(region + cb.dst_dw[l] + 8u * c);
    u4 o0 = {o[0], o[1], o[2], o[3]};
    u4 o1 = {o[4], o[5], o[6], o[7]};
    dst[0] = o0; dst[1] = o1;
}

// ---------------- per-hash-level encode: 4 pts/thread -----------------------
// x-corner pair {c0^R, (c0+1)^R}: for c0 % 4 != 3, d = c0^(c0+1) is 1 or 3 and
// both corners lie in the same aligned 4-entry (16B) block -> ONE dwordx4 per
// (y,z)-combo = 4 requests/pt (75% of points). c0 % 4 == 3: 8-dword path.
__global__ __launch_bounds__(256, 4)
void encode_hash4(const float* __restrict__ x, const unsigned* __restrict__ tb,
                  unsigned* __restrict__ hout, int N, float rf, float rm1)
{
    int j = blockIdx.x * 256 + threadIdx.x;
    int i0 = 4 * j;
    if (i0 >= N) return;

    if (i0 + 4 <= N) {
        const f4* xp = (const f4*)(x + (size_t)3 * i0);
        f4 q0 = __builtin_nontemporal_load(xp);
        f4 q1 = __builtin_nontemporal_load(xp + 1);
        f4 q2 = __builtin_nontemporal_load(xp + 2);
        float n0[4], n1[4], n2[4];
        n0[0] = (q0.x + 1.f) * 0.5f; n1[0] = (q0.y + 1.f) * 0.5f; n2[0] = (q0.z + 1.f) * 0.5f;
        n0[1] = (q0.w + 1.f) * 0.5f; n1[1] = (q1.x + 1.f) * 0.5f; n2[1] = (q1.y + 1.f) * 0.5f;
        n0[2] = (q1.z + 1.f) * 0.5f; n1[2] = (q1.w + 1.f) * 0.5f; n2[2] = (q2.x + 1.f) * 0.5f;
        n0[3] = (q2.y + 1.f) * 0.5f; n1[3] = (q2.z + 1.f) * 0.5f; n2[3] = (q2.w + 1.f) * 0.5f;

        unsigned o[4];
#pragma unroll
        for (int p = 0; p < 4; ++p) {
            float a0 = n0[p] * rf, a1 = n1[p] * rf, a2 = n2[p] * rf;
            float w0 = fminf(floorf(a0), rm1);
            float w1 = fminf(floorf(a1), rm1);
            float w2 = fminf(floorf(a2), rm1);
            float f0 = a0 - w0, f1 = a1 - w1, f2 = a2 - w2;
            unsigned c0 = (unsigned)w0;
            unsigned hx0 = c0;
            unsigned hy0 = (unsigned)w1 * PR1, hy1 = hy0 + PR1;
            unsigned hz0 = (unsigned)w2 * PR2, hz1 = hz0 + PR2;
            float wx1 = f0, wx0 = 1.f - f0;

            float acc0, acc1;
            if ((c0 & 3u) != 3u) {
                // d = 1 (even) or 3 (c0 % 4 == 1): pair within aligned-4 block
                unsigned d = (c0 & 1u) ? 3u : 1u;
                unsigned offb[4], qs[4];
#pragma unroll
                for (int jj = 0; jj < 4; ++jj) {
                    unsigned hyv = (jj & 2) ? hy1 : hy0;
                    unsigned hzv = (jj & 1) ? hz1 : hz0;
                    unsigned idx0 = (hx0 ^ hyv ^ hzv) & (TBL - 1u);
                    qs[jj] = idx0 & 3u;
                    offb[jj] = (idx0 & ~3u) << 2;
                }
                u4 bv[4];
                gather4x4_sc0(tb, offb, bv);
                acc0 = 0.f; acc1 = 0.f;
#pragma unroll
                for (int jj = 0; jj < 4; ++jj) {
                    unsigned q = qs[jj];
                    unsigned x0v = sel4(bv[jj], q);        // corner x = c0
                    unsigned x1v = sel4(bv[jj], q ^ d);    // corner x = c0+1
                    float wyz = ((jj & 2) ? f1 : 1.f - f1) * ((jj & 1) ? f2 : 1.f - f2);
                    acc0 = fmaf(wyz, fmaf(wx0, bf_lo(x0v), wx1 * bf_lo(x1v)), acc0);
                    acc1 = fmaf(wyz, fmaf(wx0, bf_hi(x0v), wx1 * bf_hi(x1v)), acc1);
                }
            } else {
                unsigned hx1 = c0 + 1u;
                unsigned off[8];
#pragma unroll
                for (int c = 0; c < 8; ++c) {
                    unsigned hx = (c & 4) ? hx1 : hx0;
                    unsigned hy = (c & 2) ? hy1 : hy0;
                    unsigned hz = (c & 1) ? hz1 : hz0;
                    off[c] = ((hx ^ hy ^ hz) & (TBL - 1u)) << 2;
                }
                unsigned v[8];
                gather8_sc0(tb, off, v);
                acc0 = 0.f; acc1 = 0.f;
#pragma unroll
                for (int c = 0; c < 8; ++c) {
                    float w = ((c & 4) ? f0 : 1.f - f0) *
                              ((c & 2) ? f1 : 1.f - f1) *
                              ((c & 1) ? f2 : 1.f - f2);
                    acc0 = fmaf(w, bf_lo(v[c]), acc0);
                    acc1 = fmaf(w, bf_hi(v[c]), acc1);
                }
            }
            o[p] = (f2bf(acc1) << 16) | f2bf(acc0);
        }
        u4 ov = {o[0], o[1], o[2], o[3]};
        __builtin_nontemporal_store(ov, (u4*)(hout + i0));
    } else {
        for (int i = i0; i < N; ++i) {
            float xn0 = (x[3 * i + 0] + 1.0f) * 0.5f;
            float xn1 = (x[3 * i + 1] + 1.0f) * 0.5f;
            float xn2 = (x[3 * i + 2] + 1.0f) * 0.5f;
            float p0 = xn0 * rf, p1 = xn1 * rf, p2 = xn2 * rf;
            float pf0 = fminf(floorf(p0), rm1), pf1 = fminf(floorf(p1), rm1), pf2 = fminf(floorf(p2), rm1);
            float fg0 = p0 - pf0, fg1 = p1 - pf1, fg2 = p2 - pf2;
            unsigned hx0 = (unsigned)pf0, hx1 = hx0 + 1u;
            unsigned hy0 = (unsigned)pf1 * PR1, hy1 = hy0 + PR1;
            unsigned hz0 = (unsigned)pf2 * PR2, hz1 = hz0 + PR2;
            float a0 = 0.f, a1 = 0.f;
#pragma unroll
            for (int c = 0; c < 8; ++c) {
                unsigned hxv = (c & 4) ? hx1 : hx0;
                unsigned hyv = (c & 2) ? hy1 : hy0;
                unsigned hzv = (c & 1) ? hz1 : hz0;
                unsigned vv = tb[(hxv ^ hyv ^ hzv) & (TBL - 1u)];
                float w = ((c & 4) ? fg0 : 1.f - fg0) * ((c & 2) ? fg1 : 1.f - fg1) * ((c & 1) ? fg2 : 1.f - fg2);
                a0 = fmaf(w, bf_lo(vv), a0);
                a1 = fmaf(w, bf_hi(vv), a1);
            }
            hout[i] = (f2bf(a1) << 16) | f2bf(a0);
        }
    }
}

// trilinear blend of one 32B cell (two 16B halves, z=0/1)
static __device__ __forceinline__ unsigned blend_cell(u4 e0, u4 e1,
                                                      float fx, float fy, float fz)
{
    float wx1 = fx, wx0 = 1.f - fx;
    float wy1 = fy, wy0 = 1.f - fy;
    float lo0 = wy0 * fmaf(wx0, bf_lo(e0[0]), wx1 * bf_lo(e0[1]))
              + wy1 * fmaf(wx0, bf_lo(e0[2]), wx1 * bf_lo(e0[3]));
    float hi0 = wy0 * fmaf(wx0, bf_hi(e0[0]), wx1 * bf_hi(e0[1]))
              + wy1 * fmaf(wx0, bf_hi(e0[2]), wx1 * bf_hi(e0[3]));
    float lo1 = wy0 * fmaf(wx0, bf_lo(e1[0]), wx1 * bf_lo(e1[1]))
              + wy1 * fmaf(wx0, bf_lo(e1[2]), wx1 * bf_lo(e1[3]));
    float hi1 = wy0 * fmaf(wx0, bf_hi(e1[0]), wx1 * bf_hi(e1[1]))
              + wy1 * fmaf(wx0, bf_hi(e1[2]), wx1 * bf_hi(e1[3]));
    float acc0 = (1.f - fz) * lo0 + fz * lo1;
    float acc1 = (1.f - fz) * hi0 + fz * hi1;
    return (f2bf(acc1) << 16) | f2bf(acc0);
}

// ---------------- final: 7 cell levels + hbuf + MFMA MLP --------------------
// Requires N % 256 == 0 (guaranteed by fast-path guard).
__global__ __launch_bounds__(256, 4)
void final_mfma(const float* __restrict__ x, const unsigned* __restrict__ tb,
                const unsigned* __restrict__ hbuf, const unsigned* __restrict__ w1bf,
                const float* __restrict__ b1, const float* __restrict__ w2,
                const float* __restrict__ b2, float* __restrict__ out,
                int N, FinalParams dp)
{
    __shared__ unsigned lds[256 * 20];   // 80B-stride rows, 16B-aligned chunks
    __shared__ unsigned olds[768];       // coalesced output staging
    int tid = threadIdx.x;
    int i = blockIdx.x * 256 + tid;

    unsigned hp[NHASH];
#pragma unroll
    for (int l = 0; l < NHASH; ++l)
        hp[l] = __builtin_nontemporal_load(hbuf + (size_t)l * N + i);

    float xn0 = (__builtin_nontemporal_load(x + 3 * i + 0) + 1.0f) * 0.5f;
    float xn1 = (__builtin_nontemporal_load(x + 3 * i + 1) + 1.0f) * 0.5f;
    float xn2 = (__builtin_nontemporal_load(x + 3 * i + 2) + 1.0f) * 0.5f;

    float fr[NDENSE][3];
    unsigned offs[2 * NDENSE];
#pragma unroll
    for (int l = 0; l < NDENSE; ++l) {
        float rf = dp.resf[l];
        float p0 = xn0 * rf, p1 = xn1 * rf, p2 = xn2 * rf;
        float pf0 = fminf(floorf(p0), dp.resm1[l]);
        float pf1 = fminf(floorf(p1), dp.resm1[l]);
        float pf2 = fminf(floorf(p2), dp.resm1[l]);
        fr[l][0] = p0 - pf0; fr[l][1] = p1 - pf1; fr[l][2] = p2 - pf2;
        unsigned c = (unsigned)pf0 + (unsigned)pf1 * dp.cres[l] + (unsigned)pf2 * dp.cres2[l];
        unsigned base = dp.cellbase[l] + c * 32u;
        offs[2 * l + 0] = base;
        offs[2 * l + 1] = base + 16u;
    }

    unsigned hw[16];
    {
        u4 xv[10];
        gather10x4_sc0(tb, offs, xv);
#pragma unroll
        for (int l = 0; l < 5; ++l)
            hw[l] = blend_cell(xv[2 * l], xv[2 * l + 1], fr[l][0], fr[l][1], fr[l][2]);
    }
    {
        u4 yv[4];
        gather4x4_sc0(tb, offs + 10, yv);
        hw[5] = blend_cell(yv[0], yv[1], fr[5][0], fr[5][1], fr[5][2]);
        hw[6] = blend_cell(yv[2], yv[3], fr[6][0], fr[6][1], fr[6][2]);
    }
#pragma unroll
    for (int l = 0; l < NHASH; ++l) hw[NDENSE + l] = hp[l];

    unsigned* row = &lds[tid * 20];
#pragma unroll
    for (int c = 0; c < 4; ++c)
        *(uint4*)(row + 4 * c) = make_uint4(hw[4 * c], hw[4 * c + 1], hw[4 * c + 2], hw[4 * c + 3]);

    __syncthreads();

    // ---- phase B: MFMA MLP, 16 points per group, 4 groups per wave ----
    int lane = tid & 63;
    int wv   = tid >> 6;
    int l16  = lane & 15;
    int lhi  = lane >> 4;

    bf16x8 bfr[4];
#pragma unroll
    for (int t = 0; t < 4; ++t) {
        const unsigned* p = w1bf + (t * 16 + l16) * 16 + lhi * 4;
        FragU u;
        u.u[0] = p[0]; u.u[1] = p[1]; u.u[2] = p[2]; u.u[3] = p[3];
        bfr[t] = u.v;
    }
    float b1v[4];
#pragma unroll
    for (int t = 0; t < 4; ++t) b1v[t] = b1[t * 16 + l16];
    float w2v[3][4];
#pragma unroll
    for (int jj = 0; jj < 3; ++jj)
#pragma unroll
        for (int t = 0; t < 4; ++t) w2v[jj][t] = w2[jj * 64 + t * 16 + l16];
    float bias2 = (l16 < 3) ? b2[l16] : 0.f;

#pragma unroll
    for (int g = 0; g < 4; ++g) {
        const unsigned* rp = &lds[(wv * 64 + g * 16 + l16) * 20 + lhi * 4];
        FragU u;
        u.u[0] = rp[0]; u.u[1] = rp[1]; u.u[2] = rp[2]; u.u[3] = rp[3];
        bf16x8 af = u.v;

        f32x4 acc[4];
#pragma unroll
        for (int t = 0; t < 4; ++t) {
            f32x4 z = {0.f, 0.f, 0.f, 0.f};
            acc[t] = __builtin_amdgcn_mfma_f32_16x16x32_bf16(af, bfr[t], z, 0, 0, 0);
        }

#pragma unroll
        for (int r = 0; r < 4; ++r) {
            float p0 = 0.f, p1 = 0.f, p2 = 0.f;
#pragma unroll
            for (int t = 0; t < 4; ++t) {
                float a = fmaxf(acc[t][r] + b1v[t], 0.f);
                p0 = fmaf(a, w2v[0][t], p0);
                p1 = fmaf(a, w2v[1][t], p1);
                p2 = fmaf(a, w2v[2][t], p2);
            }
#pragma unroll
            for (int m = 1; m < 16; m <<= 1) {
                p0 += __shfl_xor(p0, m);
                p1 += __shfl_xor(p1, m);
                p2 += __shfl_xor(p2, m);
            }
            if (l16 < 3) {
                int plocal = wv * 64 + g * 16 + lhi * 4 + r;
                float v = (l16 == 0) ? p0 : ((l16 == 1) ? p1 : p2);
                olds[plocal * 3 + l16] = __float_as_uint(fast_tanh(v + bias2));
            }
        }
    }

    __syncthreads();

    // coalesced output: 768 dwords per block, 3 per thread
    unsigned* ob = (unsigned*)out + (size_t)blockIdx.x * 768;
    __builtin_nontemporal_store(olds[tid],       ob + tid);
    __builtin_nontemporal_store(olds[tid + 256], ob + tid + 256);
    __builtin_nontemporal_store(olds[tid + 512], ob + tid + 512);
}

// ---------------- fallback: round-1 fused kernel (proven correct) -----------
__global__ __launch_bounds__(256)
void fused_ngp(const float* __restrict__ x, const float* __restrict__ tables,
               const float* __restrict__ w1, const float* __restrict__ b1,
               const float* __restrict__ w2, const float* __restrict__ b2,
               float* __restrict__ out, int N, EncParams ep)
{
    int i = blockIdx.x * 256 + threadIdx.x;
    if (i >= N) return;

    float xn0 = (x[3 * i + 0] + 1.0f) * 0.5f;
    float xn1 = (x[3 * i + 1] + 1.0f) * 0.5f;
    float xn2 = (x[3 * i + 2] + 1.0f) * 0.5f;

    float h[2 * LVL];

#pragma unroll
    for (int l = 0; l < LVL; ++l) {
        float rf = ep.resf[l];
        float p0 = xn0 * rf, p1 = xn1 * rf, p2 = xn2 * rf;
        float pf0 = fminf(floorf(p0), ep.resm1[l]);
        float pf1 = fminf(floorf(p1), ep.resm1[l]);
        float pf2 = fminf(floorf(p2), ep.resm1[l]);
        float fr0 = p0 - pf0, fr1 = p1 - pf1, fr2 = p2 - pf2;
        unsigned c0 = (unsigned)pf0, c1 = (unsigned)pf1, c2 = (unsigned)pf2;
        const float2* tb = (const float2*)tables + (size_t)l * TBL;

        float acc0 = 0.f, acc1 = 0.f;
        if ((ep.dense_mask >> l) & 1u) {
            unsigned s1 = ep.s1[l], s2 = ep.s2[l];
            unsigned b = c0 + c1 * s1 + c2 * s2;
#pragma unroll
            for (int c = 0; c < 8; ++c) {
                unsigned id = b + ((c & 4) ? 1u : 0u) + ((c & 2) ? s1 : 0u) + ((c & 1) ? s2 : 0u);
                float2 v = tb[id];
                float w = ((c & 4) ? fr0 : 1.f - fr0) * ((c & 2) ? fr1 : 1.f - fr1) * ((c & 1) ? fr2 : 1.f - fr2);
                acc0 = fmaf(w, v.x, acc0);
                acc1 = fmaf(w, v.y, acc1);
            }
        } else {
            unsigned hx0 = c0, hx1 = c0 + 1u;
            unsigned hy0 = c1 * PR1, hy1 = hy0 + PR1;
            unsigned hz0 = c2 * PR2, hz1 = hz0 + PR2;
#pragma unroll
            for (int c = 0; c < 8; ++c) {
                unsigned hx = (c & 4) ? hx1 : hx0;
                unsigned hy = (c & 2) ? hy1 : hy0;
                unsigned hz = (c & 1) ? hz1 : hz0;
                float2 v = tb[(hx ^ hy ^ hz) & (TBL - 1u)];
                float w = ((c & 4) ? fr0 : 1.f - fr0) * ((c & 2) ? fr1 : 1.f - fr1) * ((c & 1) ? fr2 : 1.f - fr2);
                acc0 = fmaf(w, v.x, acc0);
                acc1 = fmaf(w, v.y, acc1);
            }
        }
        h[2 * l + 0] = acc0;
        h[2 * l + 1] = acc1;
    }

    float r0 = b2[0], r1 = b2[1], r2 = b2[2];
    for (int o = 0; o < 64; ++o) {
        float a = b1[o];
#pragma unroll
        for (int k = 0; k < 32; ++k) a = fmaf(h[k], w1[o * 32 + k], a);
        a = fmaxf(a, 0.f);
        r0 = fmaf(a, w2[0 * 64 + o], r0);
        r1 = fmaf(a, w2[1 * 64 + o], r1);
        r2 = fmaf(a, w2[2 * 64 + o], r2);
    }
    out[3 * i + 0] = tanhf(r0);
    out[3 * i + 1] = tanhf(r1);
    out[3 * i + 2] = tanhf(r2);
}

// ---------------------------------------------------------------------------
extern "C" void kernel_launch(void* const* d_in, const int* in_sizes, int n_in,
                              void* d_out, int out_size, void* d_ws, size_t ws_size,
                              hipStream_t stream)
{
    const float* x      = (const float*)d_in[0];
    const float* tables = (const float*)d_in[1];
    const float* v1     = (const float*)d_in[2];
    const float* g1     = (const float*)d_in[3];
    const float* b1     = (const float*)d_in[4];
    const float* v2     = (const float*)d_in[5];
    const float* g2     = (const float*)d_in[6];
    const float* b2     = (const float*)d_in[7];
    float* out = (float*)d_out;
    float* ws  = (float*)d_ws;
    int N = in_sizes[0] / 3;

    // Replicate reference's double-precision level math exactly.
    EncParams ep;
    double Bd = exp(log(512.0 / 16.0) / (double)(LVL - 1));
    unsigned dm = 0;
    int resv[LVL];
    for (int l = 0; l < LVL; ++l) {
        int res = (int)floor(16.0 * pow(Bd, (double)l));
        resv[l] = res;
        ep.resf[l]  = (float)res;
        ep.resm1[l] = (float)(res - 1);
        long long rp1 = (long long)res + 1;
        if (rp1 * rp1 * rp1 <= (long long)TBL) dm |= (1u << l);
        ep.s1[l] = (unsigned)(res + 1);
        ep.s2[l] = (unsigned)((res + 1) * (res + 1));
    }
    ep.dense_mask = dm;

    prep_weights<<<1, 256, 0, stream>>>(v1, g1, v2, g2, ws);

    // workspace layout (bytes):
    //   [0, 16K)              weights
    //   [16K, 16K+32M)        16 level slots (2MB each):
    //                           slots 0-4: cell tables (built from fp32 src)
    //                           slots 7-15: bf16 tables (encode)
    //                           slots 5,6: unused
    //   [+..]                 cell tables for levels 5, 6 (32B/cell)
    //   [+..]                 hbuf
    size_t tb_off_bytes = 16384;
    unsigned NC[NDENSE];
    for (int l = 0; l < NDENSE; ++l) {
        unsigned r = (unsigned)resv[l];
        NC[l] = r * r * r;
    }
    bool cell_ok = true;
    for (int l = 0; l < 5; ++l) if (8ull * NC[l] > TBL) cell_ok = false;

    unsigned cum_dw = LVL * TBL;
    cum_dw = (cum_dw + 15u) & ~15u;
    unsigned cell5_dw = cum_dw; cum_dw += (8u * NC[5] + 15u) & ~15u;
    unsigned cell6_dw = cum_dw; cum_dw += (8u * NC[6] + 15u) & ~15u;
    size_t h_off_bytes = tb_off_bytes + (size_t)cum_dw * 4;
    size_t need = h_off_bytes + (size_t)NHASH * (size_t)N * 4;

    bool fast = (ws_size >= need) && (dm == 0x7Fu) && (N % 1024 == 0) && cell_ok;
    if (fast) {
        unsigned* tb   = (unsigned*)((char*)d_ws + tb_off_bytes);
        unsigned* hbuf = (unsigned*)((char*)d_ws + h_off_bytes);
        unsigned* w1bf = (unsigned*)ws + 2304;

        // convert only hash levels 7..15 (dense slots unused in fast path)
        int npairs = (int)((size_t)(LVL - NDENSE) * TBL / 2);
        convert_tables<<<(npairs + 255) / 256, 256, 0, stream>>>(
            tables + (size_t)NDENSE * TBL * 2, tb + (size_t)NDENSE * TBL, npairs);

        // 32B cell tables: levels 0-4 in-slot, 5-6 in extra region (fp32 source)
        CellBuild cb;
        unsigned maxNC = 0;
        for (int l = 0; l < NDENSE; ++l) {
            cb.nc[l] = NC[l]; cb.res[l] = (unsigned)resv[l];
            cb.s1[l] = ep.s1[l]; cb.s2[l] = ep.s2[l];
            cb.dst_dw[l] = (l < 5) ? (unsigned)l * TBL
                                   : ((l == 5) ? cell5_dw : cell6_dw);
            if (NC[l] > maxNC) maxNC = NC[l];
        }
        dim3 cgrid((maxNC + 255) / 256, NDENSE);
        build_cell<<<cgrid, 256, 0, stream>>>(tables, tb, cb);

        int grid4 = N / 1024;
        for (int l = 0; l < NHASH; ++l) {
            int gl = NDENSE + l;
            encode_hash4<<<grid4, 256, 0, stream>>>(
                x, tb + (size_t)gl * TBL, hbuf + (size_t)l * N, N,
                ep.resf[gl], ep.resm1[gl]);
        }

        FinalParams dp;
        for (int l = 0; l < NDENSE; ++l) {
            dp.resf[l] = ep.resf[l]; dp.resm1[l] = ep.resm1[l];
            dp.cellbase[l] = ((l < 5) ? (unsigned)l * TBL
                                      : ((l == 5) ? cell5_dw : cell6_dw)) * 4u;
            dp.cres[l] = (unsigned)resv[l];
            dp.cres2[l] = (unsigned)(resv[l] * resv[l]);
        }
        final_mfma<<<N / 256, 256, 0, stream>>>(x, tb, hbuf, w1bf, b1,
                                                ws + 2048, b2, out, N, dp);
    } else {
        fused_ngp<<<(N + 255) / 256, 256, 0, stream>>>(x, tables, ws, b1, ws + 2048, b2, out, N, ep);
    }
}